// Round 6
// baseline (168.487 us; speedup 1.0000x reference)
//
#include <hip/hip_runtime.h>

// ExtractTsFeatures fused, f16-packed: x (512,1024,32) fp32 -> out (512,32,30) fp32.
// Block = 256 threads stages 8 series as f16 PAIRS (2 series per u32) into
// 16 KiB LDS; each wave owns one packed row = 2 series, 16 packed regs/lane
// (element t = q*256 + lane*4 + i in p[q*4+i]; lo = series A, hi = series B).
// Stats: f32 on unpacked halves, reduced to wave-uniform scalars (SGPRs).
// Sort: one packed bitonic merge network sorts both series (v_pk_min/max_f16);
// cross-lane selects pinned to v_cndmask_b32 with CONSTANT 64b lane masks.
// Single merged epilogue: lane0 = series A, lane1 = series B via cndmask;
// fast amdgcn sqrt/rcp; results staged in LDS, block writes 960B coalesced.

typedef _Float16 h2 __attribute__((ext_vector_type(2)));
typedef unsigned int uint;
typedef unsigned long long u64;

// constant lane-bit masks: bit set in lane l iff (l & BIT)
#define KM1  0xAAAAAAAAAAAAAAAAull
#define KM2  0xCCCCCCCCCCCCCCCCull
#define KM4  0xF0F0F0F0F0F0F0F0ull
#define KM8  0xFF00FF00FF00FF00ull
#define KM16 0xFFFF0000FFFF0000ull
#define KM32 0xFFFFFFFF00000000ull

__device__ __forceinline__ uint h2u(h2 v) { return __builtin_bit_cast(uint, v); }
__device__ __forceinline__ h2   u2h(uint v) { return __builtin_bit_cast(h2, v); }
__device__ __forceinline__ uint pkrtz(float a, float b) {
  return __builtin_bit_cast(uint, __builtin_amdgcn_cvt_pkrtz(a, b));
}
__device__ __forceinline__ uint pmin(uint a, uint b) {
  return h2u(__builtin_elementwise_min(u2h(a), u2h(b)));
}
__device__ __forceinline__ uint pmax(uint a, uint b) {
  return h2u(__builtin_elementwise_max(u2h(a), u2h(b)));
}
// pinned per-lane select: lanes with mask-bit 1 take b (max), else a (min)
__device__ __forceinline__ uint csel(uint a, uint b, u64 km) {
  uint r;
  asm("v_cndmask_b32 %0, %1, %2, %3" : "=v"(r) : "v"(a), "v"(b), "s"(km));
  return r;
}

__device__ __forceinline__ float f_i(int v) { return __int_as_float(v); }
__device__ __forceinline__ int   i_f(float v) { return __float_as_int(v); }

template <int CTRL, bool ZERO>
__device__ __forceinline__ float dppf(float x) {
  int xi = i_f(x);
  return f_i(__builtin_amdgcn_update_dpp(ZERO ? 0 : xi, xi, CTRL, 0xF, 0xF, ZERO));
}

// xor-exchange on packed u32: DPP masks 1,2,3,7,15 (VALU); swizzle 4,8,16,31.
template <int MASK>
__device__ __forceinline__ uint exu(uint x) {
  static_assert(MASK == 1 || MASK == 2 || MASK == 3 || MASK == 4 || MASK == 7 ||
                MASK == 8 || MASK == 15 || MASK == 16 || MASK == 31, "bad mask");
  if constexpr (MASK == 1)  return (uint)__builtin_amdgcn_update_dpp(0, (int)x, 0xB1, 0xF, 0xF, true);
  if constexpr (MASK == 2)  return (uint)__builtin_amdgcn_update_dpp(0, (int)x, 0x4E, 0xF, 0xF, true);
  if constexpr (MASK == 3)  return (uint)__builtin_amdgcn_update_dpp(0, (int)x, 0x1B, 0xF, 0xF, true);
  if constexpr (MASK == 7)  return (uint)__builtin_amdgcn_update_dpp(0, (int)x, 0x141, 0xF, 0xF, true);
  if constexpr (MASK == 15) return (uint)__builtin_amdgcn_update_dpp(0, (int)x, 0x140, 0xF, 0xF, true);
  if constexpr (MASK == 4)  return (uint)__builtin_amdgcn_ds_swizzle((int)x, 0x101F);
  if constexpr (MASK == 8)  return (uint)__builtin_amdgcn_ds_swizzle((int)x, 0x201F);
  if constexpr (MASK == 16) return (uint)__builtin_amdgcn_ds_swizzle((int)x, 0x401F);
  if constexpr (MASK == 31) return (uint)__builtin_amdgcn_ds_swizzle((int)x, 0x7C1F);
  return x;
}

__device__ __forceinline__ float bpermf(int addr, float x) {
  return f_i(__builtin_amdgcn_ds_bpermute(addr, i_f(x)));
}
__device__ __forceinline__ uint bpermu(int addr, uint x) {
  return (uint)__builtin_amdgcn_ds_bpermute(addr, (int)x);
}
__device__ __forceinline__ float rdl(float v, int l) {
  return f_i(__builtin_amdgcn_readlane(i_f(v), l));
}
__device__ __forceinline__ uint irdl(uint v, int l) {
  return (uint)__builtin_amdgcn_readlane((int)v, l);
}

// f32 DPP sum reduction; result (lane 63) broadcast via readlane.
__device__ __forceinline__ float red_sum(float v) {
  v += dppf<0x111, true>(v);   // row_shr:1
  v += dppf<0x112, true>(v);   // row_shr:2
  v += dppf<0x114, true>(v);   // row_shr:4
  v += dppf<0x118, true>(v);   // row_shr:8
  v += dppf<0x142, true>(v);   // row_bcast:15
  v += dppf<0x143, true>(v);   // row_bcast:31
  return rdl(v, 63);
}

// In-lane ascending bitonic sort of 16 packed pairs (compile-time directions).
__device__ __forceinline__ void sort16p(uint (&d)[16]) {
#pragma unroll
  for (int kk = 2; kk <= 16; kk <<= 1) {
#pragma unroll
    for (int j = kk >> 1; j >= 1; j >>= 1) {
#pragma unroll
      for (int r = 0; r < 16; ++r) {
        int p = r ^ j;
        if (p > r) {
          uint mn = pmin(d[r], d[p]);
          uint mx = pmax(d[r], d[p]);
          bool up = ((r & kk) == 0);
          d[r] = up ? mn : mx;
          d[p] = up ? mx : mn;
        }
      }
    }
  }
}
// In-lane ascending bitonic merge (j = 8..1).
__device__ __forceinline__ void merge16p(uint (&d)[16]) {
#pragma unroll
  for (int j = 8; j >= 1; j >>= 1) {
#pragma unroll
    for (int r = 0; r < 16; ++r) {
      int p = r ^ j;
      if (p > r) {
        uint mn = pmin(d[r], d[p]);
        d[p] = pmax(d[r], d[p]);
        d[r] = mn;
      }
    }
  }
}

// Split with reversal: pos m pairs with lane^MASK, reg 15-r.
template <int MASK>
__device__ __forceinline__ void splitp(uint (&d)[16], u64 km) {
#pragma unroll
  for (int r = 0; r < 8; ++r) {
    uint pa = exu<MASK>(d[15 - r]);
    uint pb = exu<MASK>(d[r]);
    uint mn0 = pmin(d[r], pa),      mx0 = pmax(d[r], pa);
    uint mn1 = pmin(d[15 - r], pb), mx1 = pmax(d[15 - r], pb);
    d[r]      = csel(mn0, mx0, km);
    d[15 - r] = csel(mn1, mx1, km);
  }
}
__device__ __forceinline__ void split63p(uint (&d)[16], u64 km, int addr63) {
#pragma unroll
  for (int r = 0; r < 8; ++r) {
    uint pa = bpermu(addr63, d[15 - r]);
    uint pb = bpermu(addr63, d[r]);
    uint mn0 = pmin(d[r], pa),      mx0 = pmax(d[r], pa);
    uint mn1 = pmin(d[15 - r], pb), mx1 = pmax(d[15 - r], pb);
    d[r]      = csel(mn0, mx0, km);
    d[15 - r] = csel(mn1, mx1, km);
  }
}
// Straight merge stage at lane distance MASK.
template <int MASK>
__device__ __forceinline__ void xstp(uint (&d)[16], u64 km) {
#pragma unroll
  for (int r = 0; r < 16; ++r) {
    uint t = exu<MASK>(d[r]);
    d[r] = csel(pmin(d[r], t), pmax(d[r], t), km);
  }
}

__global__ __launch_bounds__(256, 8) void feat_fused(const float* __restrict__ x,
                                                     float* __restrict__ out) {
  __shared__ __align__(16) uint sm[4 * 1024];  // 4 packed rows x 1024 = 16 KiB
  __shared__ float stash[8 * 30];              // per-block output stage
  const int tid  = threadIdx.x;
  const int lane = tid & 63;
  const int wv   = tid >> 6;
  const int g    = blockIdx.x;
  const int b  = ((g & 7) << 6) + (g >> 5);   // XCD swizzle: siblings share L2
  const int f8 = (g >> 3) & 3;

  // ---- stage 8 series as 4 packed f16 rows ----
  const float4* xv = (const float4*)x;
  const int fq = tid & 1, t0 = tid >> 1;
  const size_t base4 = (size_t)b * 8192 + (size_t)((f8 << 1) + fq);
#pragma unroll
  for (int it = 0; it < 8; ++it) {
    int t = t0 + (it << 7);
    float4 v = xv[base4 + (size_t)t * 8];
    sm[((fq << 1) + 0) * 1024 + t] = pkrtz(v.x, v.y);
    sm[((fq << 1) + 1) * 1024 + t] = pkrtz(v.z, v.w);
  }
  __syncthreads();

  // packed series pair: lo = f8*8 + 2*wv, hi = +1
  uint p[16];
  {
    const uint* src = sm + (wv << 10);
#pragma unroll
    for (int q = 0; q < 4; ++q) {
      uint4 v = *(const uint4*)(src + (q << 8) + (lane << 2));
      p[q * 4 + 0] = v.x; p[q * 4 + 1] = v.y;
      p[q * 4 + 2] = v.z; p[q * 4 + 3] = v.w;
    }
  }

  const int addr_nx = ((lane + 1) & 63) << 2;
  const int addr63  = (lane ^ 63) << 2;
  const bool is63 = (lane == 63), is0 = (lane == 0);

  // ============== per-series stats -> wave-uniform scalars ==============
  float meanS[2], s2S[2], s3S[2], s4S[2], SDS[2], sadS[2], sddS[2];
  float tb0S[2], tb1S[2], tb2S[2], tb3S[2], tb4S[2];
  int cposS[2], cmS[2], c0S[2], c1S[2], c2S[2], c3S[2], c4S[2];

#pragma unroll
  for (int s = 0; s < 2; ++s) {
    float u[16];
    if (s == 0) {
#pragma unroll
      for (int r = 0; r < 16; ++r) u[r] = (float)u2h(p[r]).x;
    } else {
#pragma unroll
      for (int r = 0; r < 16; ++r) u[r] = (float)u2h(p[r]).y;
    }

    // tb values at t = 0, 256, 512, 767, 1023
    float tb0 = rdl(u[0], 0);
    float tb1 = rdl(u[4], 0);
    float tb2 = rdl(u[8], 0);
    float tb3 = rdl(u[11], 63);
    float tb4 = rdl(u[15], 63);

    // raw moments (f32)
    float s1 = 0.f, s2 = 0.f, s3 = 0.f, s4 = 0.f;
#pragma unroll
    for (int r = 0; r < 16; ++r) {
      float v = u[r], v2 = v * v;
      s1 += v;
      s2 = fmaf(v, v, s2);
      s3 = fmaf(v2, v, s3);
      s4 = fmaf(v2, v2, s4);
    }
    s1 = red_sum(s1);
    float mean = s1 * (1.0f / 1024.0f);

    // counts via ballot+popcount
    int cpos = 0, cm = 0, c0 = 0, c1 = 0, c2 = 0, c3 = 0, c4 = 0;
#pragma unroll
    for (int r = 0; r < 16; ++r) {
      float v = u[r];
      cpos += __popcll(__ballot(v > 0.f));
      cm   += __popcll(__ballot(v > mean));
      c0   += __popcll(__ballot(v > tb0));
      c1   += __popcll(__ballot(v > tb1));
      c2   += __popcll(__ballot(v > tb2));
      c3   += __popcll(__ballot(v > tb3));
      c4   += __popcll(__ballot(v > tb4));
    }

    // diffs d_t = x[t]-x[t+1], t in [1,1022]; sum telescopes.
    float j1 = rdl(u[4], 0), j2 = rdl(u[8], 0), j3 = rdl(u[12], 0);
    float x1v = rdl(u[1], 0), x1023 = rdl(u[15], 63);
    float sad = 0.f, sdd = 0.f;
#pragma unroll
    for (int q = 0; q < 4; ++q) {
      float nv = bpermf(addr_nx, u[q * 4]);
      if (q == 0) nv = is63 ? j1 : nv;
      if (q == 1) nv = is63 ? j2 : nv;
      if (q == 2) nv = is63 ? j3 : nv;
#pragma unroll
      for (int i = 0; i < 4; ++i) {
        float xn = (i < 3) ? u[q * 4 + i + 1] : nv;
        float dv = u[q * 4 + i] - xn;
        if (q == 0 && i == 0) dv = is0 ? 0.f : dv;
        if (q == 3 && i == 3) dv = is63 ? 0.f : dv;
        sad += fabsf(dv);
        sdd = fmaf(dv, dv, sdd);
      }
    }

    meanS[s] = mean;
    s2S[s] = red_sum(s2); s3S[s] = red_sum(s3); s4S[s] = red_sum(s4);
    sadS[s] = red_sum(sad); sddS[s] = red_sum(sdd);
    SDS[s] = x1v - x1023;
    tb0S[s] = tb0; tb1S[s] = tb1; tb2S[s] = tb2; tb3S[s] = tb3; tb4S[s] = tb4;
    cposS[s] = cpos; cmS[s] = cm;
    c0S[s] = c0; c1S[s] = c1; c2S[s] = c2; c3S[s] = c3; c4S[s] = c4;
  }

  // ================= packed sort (both series at once) =====================
  sort16p(p);
  splitp<1>(p, KM1);  merge16p(p);
  splitp<3>(p, KM2);  xstp<1>(p, KM1); merge16p(p);
  splitp<7>(p, KM4);  xstp<2>(p, KM2); xstp<1>(p, KM1); merge16p(p);
  splitp<15>(p, KM8); xstp<4>(p, KM4); xstp<2>(p, KM2); xstp<1>(p, KM1);
  merge16p(p);
  splitp<31>(p, KM16); xstp<8>(p, KM8); xstp<4>(p, KM4); xstp<2>(p, KM2);
  xstp<1>(p, KM1); merge16p(p);
  split63p(p, KM32, addr63);
  xstp<16>(p, KM16);

  // Pruned tail: 16-lane groups hold rank blocks {0-255,256-511,512-767,768-1023}.
  uint mnv = p[0], mxv = p[0];
#pragma unroll
  for (int r = 1; r < 16; ++r) { mnv = pmin(mnv, p[r]); mxv = pmax(mxv, p[r]); }
  mnv = pmin(mnv, exu<1>(mnv)); mxv = pmax(mxv, exu<1>(mxv));
  mnv = pmin(mnv, exu<2>(mnv)); mxv = pmax(mxv, exu<2>(mxv));
  mnv = pmin(mnv, exu<4>(mnv)); mxv = pmax(mxv, exu<4>(mxv));
  mnv = pmin(mnv, exu<8>(mnv)); mxv = pmax(mxv, exu<8>(mxv));

  uint g0n = irdl(mnv, 0);    // rank 0    (min)
  uint g1n = irdl(mnv, 16);   // rank 256  (q1)
  uint g2n = irdl(mnv, 32);   // rank 512  (q2)
  uint g2x = irdl(mxv, 32);   // rank 767  (q3)
  uint g3x = irdl(mxv, 48);   // rank 1023 (max)

  // ================= merged epilogue: lane0 = A, lane1 = B =================
  {
    const bool L1 = (lane == 1);
    float mean = L1 ? meanS[1] : meanS[0];
    float s2   = L1 ? s2S[1]   : s2S[0];
    float s3   = L1 ? s3S[1]   : s3S[0];
    float s4   = L1 ? s4S[1]   : s4S[0];
    float SD   = L1 ? SDS[1]   : SDS[0];
    float sad  = L1 ? sadS[1]  : sadS[0];
    float sdd  = L1 ? sddS[1]  : sddS[0];
    float tb0  = L1 ? tb0S[1]  : tb0S[0];
    float tb1  = L1 ? tb1S[1]  : tb1S[0];
    float tb2  = L1 ? tb2S[1]  : tb2S[0];
    float tb3  = L1 ? tb3S[1]  : tb3S[0];
    float tb4  = L1 ? tb4S[1]  : tb4S[0];
    float fcpos = (float)(L1 ? cposS[1] : cposS[0]);
    float fcm   = (float)(L1 ? cmS[1]   : cmS[0]);
    float fc0   = (float)(L1 ? c0S[1]   : c0S[0]);
    float fc1   = (float)(L1 ? c1S[1]   : c1S[0]);
    float fc2   = (float)(L1 ? c2S[1]   : c2S[0]);
    float fc3   = (float)(L1 ? c3S[1]   : c3S[0]);
    float fc4   = (float)(L1 ? c4S[1]   : c4S[0]);
    float mnf = L1 ? (float)u2h(g0n).y : (float)u2h(g0n).x;
    float q1f = L1 ? (float)u2h(g1n).y : (float)u2h(g1n).x;
    float q2f = L1 ? (float)u2h(g2n).y : (float)u2h(g2n).x;
    float q3f = L1 ? (float)u2h(g2x).y : (float)u2h(g2x).x;
    float mxf = L1 ? (float)u2h(g3x).y : (float)u2h(g3x).x;

    if (lane < 2) {
      float ex2 = s2 * (1.0f / 1024.0f);
      float rms = __builtin_amdgcn_sqrtf(fmaxf(ex2, 0.f));
      float var = fmaxf(ex2 - mean * mean, 0.f);
      float stdv = __builtin_amdgcn_sqrtf(var);
      float m2 = mean * mean;
      float m3c = s3 - 3.f * mean * s2 + 2048.f * m2 * mean;
      const float coef3 = (float)(1024.0 / (1023.0 * 1022.0));
      float den3 = stdv * stdv * stdv;
      float skew = (den3 > 0.f) ? coef3 * m3c * __builtin_amdgcn_rcpf(den3) : 0.f;
      float k4c = s4 - 4.f * mean * s3 + 6.f * m2 * s2 - 3072.f * m2 * m2;
      float s2c = s2 - 1024.f * m2;
      float k22 = s2c * s2c;
      const float alpha = (float)(1024.0 * 1025.0 * 1023.0 / (1022.0 * 1021.0));
      const float rightc = (float)(3.0 * 1023.0 * 1023.0 / (1022.0 * 1021.0));
      float kurt = (k22 > 0.f) ? alpha * k4c * __builtin_amdgcn_rcpf(k22) - rightc
                               : -rightc;

      float* o = stash + ((wv << 1) + lane) * 30;
      o[0] = mean;  o[1] = mnf;  o[2] = mxf;  o[3] = rms;
      o[4] = var;   o[5] = stdv; o[6] = skew; o[7] = kurt;
      o[8] = SD * (1.0f / 1022.0f);
      o[9] = SD;
      o[10] = sad * (1.0f / 1022.0f);
      o[11] = q1f;  o[12] = q2f; o[13] = q3f;
      o[14] = tb0;  o[15] = tb1; o[16] = tb2; o[17] = tb3; o[18] = tb4;
      o[19] = s2;
      o[20] = fmaxf(fabsf(mnf), fabsf(mxf));
      o[21] = sad;
      o[22] = __builtin_amdgcn_sqrtf(fmaxf(sdd, 0.f));
      o[23] = fcpos; o[24] = fcm;
      o[25] = fc0;   o[26] = fc1; o[27] = fc2; o[28] = fc3; o[29] = fc4;
    }
  }

  // ---- coalesced block output: 8 rows x 30 floats = 960 B contiguous ----
  __syncthreads();
  if (tid < 240) {
    size_t base = ((size_t)((b << 5) + (f8 << 3))) * 30;
    out[base + tid] = stash[tid];
  }
}

extern "C" void kernel_launch(void* const* d_in, const int* in_sizes, int n_in,
                              void* d_out, int out_size, void* d_ws, size_t ws_size,
                              hipStream_t stream) {
  const float* x = (const float*)d_in[0];
  float* out = (float*)d_out;
  hipLaunchKernelGGL(feat_fused, dim3(2048), dim3(256), 0, stream, x, out);
}

// Round 7
// 127.055 us; speedup vs baseline: 1.3261x; 1.3261x over previous
//
#include <hip/hip_runtime.h>

// ExtractTsFeatures fused, f16-packed: x (512,1024,32) fp32 -> out (512,32,30) fp32.
// Block = 256 threads stages 8 series as f16 PAIRS (2 series per u32) into
// 16 KiB LDS; each wave owns one packed row = 2 series, 16 packed regs/lane
// (element t = q*256 + lane*4 + i in p[q*4+i]; lo = series A, hi = series B).
// Stats: f32 on unpacked halves, epilogue computed and stashed to LDS INSIDE
// the per-series loop (short live ranges -- R6's merged epilogue spilled).
// Sort: one packed bitonic network sorts both series; v_pk_min/max_f16 and
// v_cndmask_b32 (constant 64b lane masks) pinned via inline asm.
// Post-sort: lane0 patches the 6 sort-derived outputs into the stash; block
// then writes 240 contiguous floats (coalesced).

typedef _Float16 h2 __attribute__((ext_vector_type(2)));
typedef unsigned int uint;
typedef unsigned long long u64;

// constant lane-bit masks: bit set in lane l iff (l & BIT)
#define KM1  0xAAAAAAAAAAAAAAAAull
#define KM2  0xCCCCCCCCCCCCCCCCull
#define KM4  0xF0F0F0F0F0F0F0F0ull
#define KM8  0xFF00FF00FF00FF00ull
#define KM16 0xFFFF0000FFFF0000ull
#define KM32 0xFFFFFFFF00000000ull

__device__ __forceinline__ h2 u2h(uint v) { return __builtin_bit_cast(h2, v); }
__device__ __forceinline__ uint pkrtz(float a, float b) {
  return __builtin_bit_cast(uint, __builtin_amdgcn_cvt_pkrtz(a, b));
}
// pinned packed min/max (guarantee v_pk_*_f16, no scalarization)
__device__ __forceinline__ uint pmin(uint a, uint b) {
  uint r; asm("v_pk_min_f16 %0, %1, %2" : "=v"(r) : "v"(a), "v"(b)); return r;
}
__device__ __forceinline__ uint pmax(uint a, uint b) {
  uint r; asm("v_pk_max_f16 %0, %1, %2" : "=v"(r) : "v"(a), "v"(b)); return r;
}
// pinned per-lane select: lanes with mask-bit 1 take b (max), else a (min)
__device__ __forceinline__ uint csel(uint a, uint b, u64 km) {
  uint r;
  asm("v_cndmask_b32 %0, %1, %2, %3" : "=v"(r) : "v"(a), "v"(b), "s"(km));
  return r;
}

__device__ __forceinline__ float f_i(int v) { return __int_as_float(v); }
__device__ __forceinline__ int   i_f(float v) { return __float_as_int(v); }

template <int CTRL, bool ZERO>
__device__ __forceinline__ float dppf(float x) {
  int xi = i_f(x);
  return f_i(__builtin_amdgcn_update_dpp(ZERO ? 0 : xi, xi, CTRL, 0xF, 0xF, ZERO));
}

// xor-exchange on packed u32: DPP masks 1,2,3,7,15 (VALU); swizzle 4,8,16,31.
template <int MASK>
__device__ __forceinline__ uint exu(uint x) {
  static_assert(MASK == 1 || MASK == 2 || MASK == 3 || MASK == 4 || MASK == 7 ||
                MASK == 8 || MASK == 15 || MASK == 16 || MASK == 31, "bad mask");
  if constexpr (MASK == 1)  return (uint)__builtin_amdgcn_update_dpp(0, (int)x, 0xB1, 0xF, 0xF, true);
  if constexpr (MASK == 2)  return (uint)__builtin_amdgcn_update_dpp(0, (int)x, 0x4E, 0xF, 0xF, true);
  if constexpr (MASK == 3)  return (uint)__builtin_amdgcn_update_dpp(0, (int)x, 0x1B, 0xF, 0xF, true);
  if constexpr (MASK == 7)  return (uint)__builtin_amdgcn_update_dpp(0, (int)x, 0x141, 0xF, 0xF, true);
  if constexpr (MASK == 15) return (uint)__builtin_amdgcn_update_dpp(0, (int)x, 0x140, 0xF, 0xF, true);
  if constexpr (MASK == 4)  return (uint)__builtin_amdgcn_ds_swizzle((int)x, 0x101F);
  if constexpr (MASK == 8)  return (uint)__builtin_amdgcn_ds_swizzle((int)x, 0x201F);
  if constexpr (MASK == 16) return (uint)__builtin_amdgcn_ds_swizzle((int)x, 0x401F);
  if constexpr (MASK == 31) return (uint)__builtin_amdgcn_ds_swizzle((int)x, 0x7C1F);
  return x;
}

__device__ __forceinline__ float bpermf(int addr, float x) {
  return f_i(__builtin_amdgcn_ds_bpermute(addr, i_f(x)));
}
__device__ __forceinline__ uint bpermu(int addr, uint x) {
  return (uint)__builtin_amdgcn_ds_bpermute(addr, (int)x);
}
__device__ __forceinline__ float rdl(float v, int l) {
  return f_i(__builtin_amdgcn_readlane(i_f(v), l));
}
__device__ __forceinline__ uint irdl(uint v, int l) {
  return (uint)__builtin_amdgcn_readlane((int)v, l);
}

// f32 DPP sum reduction; result (lane 63) broadcast via readlane.
__device__ __forceinline__ float red_sum(float v) {
  v += dppf<0x111, true>(v);   // row_shr:1
  v += dppf<0x112, true>(v);   // row_shr:2
  v += dppf<0x114, true>(v);   // row_shr:4
  v += dppf<0x118, true>(v);   // row_shr:8
  v += dppf<0x142, true>(v);   // row_bcast:15
  v += dppf<0x143, true>(v);   // row_bcast:31
  return rdl(v, 63);
}

// In-lane ascending bitonic sort of 16 packed pairs (compile-time directions).
__device__ __forceinline__ void sort16p(uint (&d)[16]) {
#pragma unroll
  for (int kk = 2; kk <= 16; kk <<= 1) {
#pragma unroll
    for (int j = kk >> 1; j >= 1; j >>= 1) {
#pragma unroll
      for (int r = 0; r < 16; ++r) {
        int p = r ^ j;
        if (p > r) {
          uint mn = pmin(d[r], d[p]);
          uint mx = pmax(d[r], d[p]);
          bool up = ((r & kk) == 0);
          d[r] = up ? mn : mx;
          d[p] = up ? mx : mn;
        }
      }
    }
  }
}
// In-lane ascending bitonic merge (j = 8..1).
__device__ __forceinline__ void merge16p(uint (&d)[16]) {
#pragma unroll
  for (int j = 8; j >= 1; j >>= 1) {
#pragma unroll
    for (int r = 0; r < 16; ++r) {
      int p = r ^ j;
      if (p > r) {
        uint mn = pmin(d[r], d[p]);
        d[p] = pmax(d[r], d[p]);
        d[r] = mn;
      }
    }
  }
}

// Split with reversal: pos m pairs with lane^MASK, reg 15-r.
template <int MASK>
__device__ __forceinline__ void splitp(uint (&d)[16], u64 km) {
#pragma unroll
  for (int r = 0; r < 8; ++r) {
    uint pa = exu<MASK>(d[15 - r]);
    uint pb = exu<MASK>(d[r]);
    uint mn0 = pmin(d[r], pa),      mx0 = pmax(d[r], pa);
    uint mn1 = pmin(d[15 - r], pb), mx1 = pmax(d[15 - r], pb);
    d[r]      = csel(mn0, mx0, km);
    d[15 - r] = csel(mn1, mx1, km);
  }
}
__device__ __forceinline__ void split63p(uint (&d)[16], u64 km, int addr63) {
#pragma unroll
  for (int r = 0; r < 8; ++r) {
    uint pa = bpermu(addr63, d[15 - r]);
    uint pb = bpermu(addr63, d[r]);
    uint mn0 = pmin(d[r], pa),      mx0 = pmax(d[r], pa);
    uint mn1 = pmin(d[15 - r], pb), mx1 = pmax(d[15 - r], pb);
    d[r]      = csel(mn0, mx0, km);
    d[15 - r] = csel(mn1, mx1, km);
  }
}
// Straight merge stage at lane distance MASK.
template <int MASK>
__device__ __forceinline__ void xstp(uint (&d)[16], u64 km) {
#pragma unroll
  for (int r = 0; r < 16; ++r) {
    uint t = exu<MASK>(d[r]);
    d[r] = csel(pmin(d[r], t), pmax(d[r], t), km);
  }
}

__global__ __launch_bounds__(256, 6) void feat_fused(const float* __restrict__ x,
                                                     float* __restrict__ out) {
  __shared__ __align__(16) uint sm[4 * 1024];  // 4 packed rows x 1024 = 16 KiB
  __shared__ float stash[8 * 30];              // per-block output stage (960 B)
  const int tid  = threadIdx.x;
  const int lane = tid & 63;
  const int wv   = tid >> 6;
  const int g    = blockIdx.x;
  const int b  = ((g & 7) << 6) + (g >> 5);   // XCD swizzle: siblings share L2
  const int f8 = (g >> 3) & 3;

  // ---- stage 8 series as 4 packed f16 rows ----
  const float4* xv = (const float4*)x;
  const int fq = tid & 1, t0 = tid >> 1;
  const size_t base4 = (size_t)b * 8192 + (size_t)((f8 << 1) + fq);
#pragma unroll
  for (int it = 0; it < 8; ++it) {
    int t = t0 + (it << 7);
    float4 v = xv[base4 + (size_t)t * 8];
    sm[((fq << 1) + 0) * 1024 + t] = pkrtz(v.x, v.y);
    sm[((fq << 1) + 1) * 1024 + t] = pkrtz(v.z, v.w);
  }
  __syncthreads();

  // packed series pair: lo = f8*8 + 2*wv, hi = +1
  uint p[16];
  {
    const uint* src = sm + (wv << 10);
#pragma unroll
    for (int q = 0; q < 4; ++q) {
      uint4 v = *(const uint4*)(src + (q << 8) + (lane << 2));
      p[q * 4 + 0] = v.x; p[q * 4 + 1] = v.y;
      p[q * 4 + 2] = v.z; p[q * 4 + 3] = v.w;
    }
  }

  const int addr_nx = ((lane + 1) & 63) << 2;
  const int addr63  = (lane ^ 63) << 2;
  const bool is63 = (lane == 63), is0 = (lane == 0);

  // ====== per-series stats; epilogue computed + stashed inside the loop ====
#pragma unroll
  for (int s = 0; s < 2; ++s) {
    float u[16];
    if (s == 0) {
#pragma unroll
      for (int r = 0; r < 16; ++r) u[r] = (float)u2h(p[r]).x;
    } else {
#pragma unroll
      for (int r = 0; r < 16; ++r) u[r] = (float)u2h(p[r]).y;
    }

    // tb values at t = 0, 256, 512, 767, 1023
    float tb0 = rdl(u[0], 0);
    float tb1 = rdl(u[4], 0);
    float tb2 = rdl(u[8], 0);
    float tb3 = rdl(u[11], 63);
    float tb4 = rdl(u[15], 63);

    // raw moments (f32)
    float s1 = 0.f, s2 = 0.f, s3 = 0.f, s4 = 0.f;
#pragma unroll
    for (int r = 0; r < 16; ++r) {
      float v = u[r], v2 = v * v;
      s1 += v;
      s2 = fmaf(v, v, s2);
      s3 = fmaf(v2, v, s3);
      s4 = fmaf(v2, v2, s4);
    }
    s1 = red_sum(s1);
    float mean = s1 * (1.0f / 1024.0f);

    // counts via ballot+popcount
    int cpos = 0, cm = 0, c0 = 0, c1 = 0, c2 = 0, c3 = 0, c4 = 0;
#pragma unroll
    for (int r = 0; r < 16; ++r) {
      float v = u[r];
      cpos += __popcll(__ballot(v > 0.f));
      cm   += __popcll(__ballot(v > mean));
      c0   += __popcll(__ballot(v > tb0));
      c1   += __popcll(__ballot(v > tb1));
      c2   += __popcll(__ballot(v > tb2));
      c3   += __popcll(__ballot(v > tb3));
      c4   += __popcll(__ballot(v > tb4));
    }

    // diffs d_t = x[t]-x[t+1], t in [1,1022]; sum telescopes.
    float j1 = rdl(u[4], 0), j2 = rdl(u[8], 0), j3 = rdl(u[12], 0);
    float x1v = rdl(u[1], 0), x1023 = rdl(u[15], 63);
    float sad = 0.f, sdd = 0.f;
#pragma unroll
    for (int q = 0; q < 4; ++q) {
      float nv = bpermf(addr_nx, u[q * 4]);
      if (q == 0) nv = is63 ? j1 : nv;
      if (q == 1) nv = is63 ? j2 : nv;
      if (q == 2) nv = is63 ? j3 : nv;
#pragma unroll
      for (int i = 0; i < 4; ++i) {
        float xn = (i < 3) ? u[q * 4 + i + 1] : nv;
        float dv = u[q * 4 + i] - xn;
        if (q == 0 && i == 0) dv = is0 ? 0.f : dv;
        if (q == 3 && i == 3) dv = is63 ? 0.f : dv;
        sad += fabsf(dv);
        sdd = fmaf(dv, dv, sdd);
      }
    }
    float SD = x1v - x1023;

    s2 = red_sum(s2); s3 = red_sum(s3); s4 = red_sum(s4);
    sad = red_sum(sad); sdd = red_sum(sdd);

    if (lane == 0) {
      float ex2 = s2 * (1.0f / 1024.0f);
      float rms = __builtin_amdgcn_sqrtf(fmaxf(ex2, 0.f));
      float var = fmaxf(ex2 - mean * mean, 0.f);
      float stdv = __builtin_amdgcn_sqrtf(var);
      float m2 = mean * mean;
      float m3c = s3 - 3.f * mean * s2 + 2048.f * m2 * mean;
      const float coef3 = (float)(1024.0 / (1023.0 * 1022.0));
      float den3 = stdv * stdv * stdv;
      float skew = (den3 > 0.f) ? coef3 * m3c * __builtin_amdgcn_rcpf(den3) : 0.f;
      float k4c = s4 - 4.f * mean * s3 + 6.f * m2 * s2 - 3072.f * m2 * m2;
      float s2c = s2 - 1024.f * m2;
      float k22 = s2c * s2c;
      const float alpha = (float)(1024.0 * 1025.0 * 1023.0 / (1022.0 * 1021.0));
      const float rightc = (float)(3.0 * 1023.0 * 1023.0 / (1022.0 * 1021.0));
      float kurt = (k22 > 0.f) ? alpha * k4c * __builtin_amdgcn_rcpf(k22) - rightc
                               : -rightc;

      float* o = stash + ((wv << 1) + s) * 30;
      o[0] = mean;  o[3] = rms;  o[4] = var;  o[5] = stdv;
      o[6] = skew;  o[7] = kurt;
      o[8] = SD * (1.0f / 1022.0f);
      o[9] = SD;
      o[10] = sad * (1.0f / 1022.0f);
      o[14] = tb0;  o[15] = tb1; o[16] = tb2; o[17] = tb3; o[18] = tb4;
      o[19] = s2;
      o[21] = sad;
      o[22] = __builtin_amdgcn_sqrtf(fmaxf(sdd, 0.f));
      o[23] = (float)cpos; o[24] = (float)cm;
      o[25] = (float)c0;   o[26] = (float)c1; o[27] = (float)c2;
      o[28] = (float)c3;   o[29] = (float)c4;
    }
  }

  // ================= packed sort (both series at once) =====================
  sort16p(p);
  splitp<1>(p, KM1);  merge16p(p);
  splitp<3>(p, KM2);  xstp<1>(p, KM1); merge16p(p);
  splitp<7>(p, KM4);  xstp<2>(p, KM2); xstp<1>(p, KM1); merge16p(p);
  splitp<15>(p, KM8); xstp<4>(p, KM4); xstp<2>(p, KM2); xstp<1>(p, KM1);
  merge16p(p);
  splitp<31>(p, KM16); xstp<8>(p, KM8); xstp<4>(p, KM4); xstp<2>(p, KM2);
  xstp<1>(p, KM1); merge16p(p);
  split63p(p, KM32, addr63);
  xstp<16>(p, KM16);

  // Pruned tail: 16-lane groups hold rank blocks {0-255,256-511,512-767,768-1023}.
  uint mnv = p[0], mxv = p[0];
#pragma unroll
  for (int r = 1; r < 16; ++r) { mnv = pmin(mnv, p[r]); mxv = pmax(mxv, p[r]); }
  mnv = pmin(mnv, exu<1>(mnv)); mxv = pmax(mxv, exu<1>(mxv));
  mnv = pmin(mnv, exu<2>(mnv)); mxv = pmax(mxv, exu<2>(mxv));
  mnv = pmin(mnv, exu<4>(mnv)); mxv = pmax(mxv, exu<4>(mxv));
  mnv = pmin(mnv, exu<8>(mnv)); mxv = pmax(mxv, exu<8>(mxv));

  uint g0n = irdl(mnv, 0);    // rank 0    (min)
  uint g1n = irdl(mnv, 16);   // rank 256  (q1)
  uint g2n = irdl(mnv, 32);   // rank 512  (q2)
  uint g2x = irdl(mxv, 32);   // rank 767  (q3)
  uint g3x = irdl(mxv, 48);   // rank 1023 (max)

  // ---- patch sort-derived outputs into the stash ----
  if (lane == 0) {
#pragma unroll
    for (int s = 0; s < 2; ++s) {
      float mnf = s ? (float)u2h(g0n).y : (float)u2h(g0n).x;
      float q1f = s ? (float)u2h(g1n).y : (float)u2h(g1n).x;
      float q2f = s ? (float)u2h(g2n).y : (float)u2h(g2n).x;
      float q3f = s ? (float)u2h(g2x).y : (float)u2h(g2x).x;
      float mxf = s ? (float)u2h(g3x).y : (float)u2h(g3x).x;
      float* o = stash + ((wv << 1) + s) * 30;
      o[1]  = mnf;
      o[2]  = mxf;
      o[11] = q1f;
      o[12] = q2f;
      o[13] = q3f;
      o[20] = fmaxf(fabsf(mnf), fabsf(mxf));
    }
  }

  // ---- coalesced block output: 8 rows x 30 floats = 960 B contiguous ----
  __syncthreads();
  if (tid < 240) {
    size_t base = ((size_t)((b << 5) + (f8 << 3))) * 30;
    out[base + tid] = stash[tid];
  }
}

extern "C" void kernel_launch(void* const* d_in, const int* in_sizes, int n_in,
                              void* d_out, int out_size, void* d_ws, size_t ws_size,
                              hipStream_t stream) {
  const float* x = (const float*)d_in[0];
  float* out = (float*)d_out;
  hipLaunchKernelGGL(feat_fused, dim3(2048), dim3(256), 0, stream, x, out);
}

// Round 8
// 125.335 us; speedup vs baseline: 1.3443x; 1.0137x over previous
//
#include <hip/hip_runtime.h>

// ExtractTsFeatures fused, f16-packed end-to-end: x (512,1024,32) fp32 -> out (512,32,30) fp32.
// Block = 256 threads stages 8 series as f16 PAIRS (2 series per u32) into
// 16 KiB LDS; each wave owns one packed row = 2 series, 16 packed regs/lane
// (element t = q*256 + lane*4 + i in p[q*4+i]; lo = series A, hi = series B).
// Stats now FULLY packed (v_pk_* does both series at once): moments, diffs,
// SD, tb, mean; packed-DPP tree reductions; counts = 1 v_cmp_gt_f16/series/reg.
// Raw stats stashed to LDS by lane0; block-level epilogue (tid<8) computes all
// 8 feature sets once. Sort: packed bitonic network (pinned v_pk_min/max_f16 +
// v_cndmask with constant 64b lane masks); xor-8 exchange = DPP row_ror:8.

typedef _Float16 h2 __attribute__((ext_vector_type(2)));
typedef unsigned int uint;
typedef unsigned long long u64;

// constant lane-bit masks: bit set in lane l iff (l & BIT)
#define KM1  0xAAAAAAAAAAAAAAAAull
#define KM2  0xCCCCCCCCCCCCCCCCull
#define KM4  0xF0F0F0F0F0F0F0F0ull
#define KM8  0xFF00FF00FF00FF00ull
#define KM16 0xFFFF0000FFFF0000ull
#define KM32 0xFFFFFFFF00000000ull
#define KML0 0x0000000000000001ull   // lane 0 only
#define KML63 0x8000000000000000ull  // lane 63 only

__device__ __forceinline__ uint h2u(h2 v) { return __builtin_bit_cast(uint, v); }
__device__ __forceinline__ h2   u2h(uint v) { return __builtin_bit_cast(h2, v); }
__device__ __forceinline__ uint pkrtz(float a, float b) {
  return __builtin_bit_cast(uint, __builtin_amdgcn_cvt_pkrtz(a, b));
}
// pinned packed min/max (guarantee v_pk_*_f16)
__device__ __forceinline__ uint pmin(uint a, uint b) {
  uint r; asm("v_pk_min_f16 %0, %1, %2" : "=v"(r) : "v"(a), "v"(b)); return r;
}
__device__ __forceinline__ uint pmax(uint a, uint b) {
  uint r; asm("v_pk_max_f16 %0, %1, %2" : "=v"(r) : "v"(a), "v"(b)); return r;
}
// pinned per-lane select: lanes with mask-bit 1 take b, else a
__device__ __forceinline__ uint csel(uint a, uint b, u64 km) {
  uint r;
  asm("v_cndmask_b32 %0, %1, %2, %3" : "=v"(r) : "v"(a), "v"(b), "s"(km));
  return r;
}

// xor-exchange on packed u32: DPP masks 1,2,3,7,8,15 (VALU); swizzle 4,16,31.
template <int MASK>
__device__ __forceinline__ uint exu(uint x) {
  static_assert(MASK == 1 || MASK == 2 || MASK == 3 || MASK == 4 || MASK == 7 ||
                MASK == 8 || MASK == 15 || MASK == 16 || MASK == 31, "bad mask");
  if constexpr (MASK == 1)  return (uint)__builtin_amdgcn_update_dpp(0, (int)x, 0xB1, 0xF, 0xF, true);
  if constexpr (MASK == 2)  return (uint)__builtin_amdgcn_update_dpp(0, (int)x, 0x4E, 0xF, 0xF, true);
  if constexpr (MASK == 3)  return (uint)__builtin_amdgcn_update_dpp(0, (int)x, 0x1B, 0xF, 0xF, true);
  if constexpr (MASK == 7)  return (uint)__builtin_amdgcn_update_dpp(0, (int)x, 0x141, 0xF, 0xF, true);
  if constexpr (MASK == 8)  return (uint)__builtin_amdgcn_update_dpp(0, (int)x, 0x128, 0xF, 0xF, true);  // row_ror:8 == xor 8
  if constexpr (MASK == 15) return (uint)__builtin_amdgcn_update_dpp(0, (int)x, 0x140, 0xF, 0xF, true);
  if constexpr (MASK == 4)  return (uint)__builtin_amdgcn_ds_swizzle((int)x, 0x101F);
  if constexpr (MASK == 16) return (uint)__builtin_amdgcn_ds_swizzle((int)x, 0x401F);
  if constexpr (MASK == 31) return (uint)__builtin_amdgcn_ds_swizzle((int)x, 0x7C1F);
  return x;
}

__device__ __forceinline__ uint bpermu(int addr, uint x) {
  return (uint)__builtin_amdgcn_ds_bpermute(addr, (int)x);
}
__device__ __forceinline__ uint irdl(uint v, int l) {
  return (uint)__builtin_amdgcn_readlane((int)v, l);
}

// packed f16 DPP tree sum (both series); result uniform via readlane 63.
__device__ __forceinline__ uint red_sum_pk(uint v) {
#define RSTEP(C) { uint t = (uint)__builtin_amdgcn_update_dpp(0, (int)v, C, 0xF, 0xF, true); \
                   v = h2u(u2h(v) + u2h(t)); }
  RSTEP(0x111) RSTEP(0x112) RSTEP(0x114) RSTEP(0x118) RSTEP(0x142) RSTEP(0x143)
#undef RSTEP
  return irdl(v, 63);
}

// In-lane ascending bitonic sort of 16 packed pairs (compile-time directions).
__device__ __forceinline__ void sort16p(uint (&d)[16]) {
#pragma unroll
  for (int kk = 2; kk <= 16; kk <<= 1) {
#pragma unroll
    for (int j = kk >> 1; j >= 1; j >>= 1) {
#pragma unroll
      for (int r = 0; r < 16; ++r) {
        int p = r ^ j;
        if (p > r) {
          uint mn = pmin(d[r], d[p]);
          uint mx = pmax(d[r], d[p]);
          bool up = ((r & kk) == 0);
          d[r] = up ? mn : mx;
          d[p] = up ? mx : mn;
        }
      }
    }
  }
}
// In-lane ascending bitonic merge (j = 8..1).
__device__ __forceinline__ void merge16p(uint (&d)[16]) {
#pragma unroll
  for (int j = 8; j >= 1; j >>= 1) {
#pragma unroll
    for (int r = 0; r < 16; ++r) {
      int p = r ^ j;
      if (p > r) {
        uint mn = pmin(d[r], d[p]);
        d[p] = pmax(d[r], d[p]);
        d[r] = mn;
      }
    }
  }
}

// Split with reversal: pos m pairs with lane^MASK, reg 15-r.
template <int MASK>
__device__ __forceinline__ void splitp(uint (&d)[16], u64 km) {
#pragma unroll
  for (int r = 0; r < 8; ++r) {
    uint pa = exu<MASK>(d[15 - r]);
    uint pb = exu<MASK>(d[r]);
    uint mn0 = pmin(d[r], pa),      mx0 = pmax(d[r], pa);
    uint mn1 = pmin(d[15 - r], pb), mx1 = pmax(d[15 - r], pb);
    d[r]      = csel(mn0, mx0, km);
    d[15 - r] = csel(mn1, mx1, km);
  }
}
__device__ __forceinline__ void split63p(uint (&d)[16], u64 km, int addr63) {
#pragma unroll
  for (int r = 0; r < 8; ++r) {
    uint pa = bpermu(addr63, d[15 - r]);
    uint pb = bpermu(addr63, d[r]);
    uint mn0 = pmin(d[r], pa),      mx0 = pmax(d[r], pa);
    uint mn1 = pmin(d[15 - r], pb), mx1 = pmax(d[15 - r], pb);
    d[r]      = csel(mn0, mx0, km);
    d[15 - r] = csel(mn1, mx1, km);
  }
}
// Straight merge stage at lane distance MASK.
template <int MASK>
__device__ __forceinline__ void xstp(uint (&d)[16], u64 km) {
#pragma unroll
  for (int r = 0; r < 16; ++r) {
    uint t = exu<MASK>(d[r]);
    d[r] = csel(pmin(d[r], t), pmax(d[r], t), km);
  }
}

__global__ __launch_bounds__(256, 6) void feat_fused(const float* __restrict__ x,
                                                     float* __restrict__ out) {
  __shared__ __align__(16) uint sm[4 * 1024];  // 4 packed rows x 1024 = 16 KiB
  __shared__ uint rawstash[4 * 20];            // per-wave raw packed stats
  __shared__ float stash[8 * 30];              // per-block output stage (960 B)
  const int tid  = threadIdx.x;
  const int lane = tid & 63;
  const int wv   = tid >> 6;
  const int g    = blockIdx.x;
  const int b  = ((g & 7) << 6) + (g >> 5);   // XCD swizzle: siblings share L2
  const int f8 = (g >> 3) & 3;

  // ---- stage 8 series as 4 packed f16 rows ----
  const float4* xv = (const float4*)x;
  const int fq = tid & 1, t0 = tid >> 1;
  const size_t base4 = (size_t)b * 8192 + (size_t)((f8 << 1) + fq);
#pragma unroll
  for (int it = 0; it < 8; ++it) {
    int t = t0 + (it << 7);
    float4 v = xv[base4 + (size_t)t * 8];
    sm[((fq << 1) + 0) * 1024 + t] = pkrtz(v.x, v.y);
    sm[((fq << 1) + 1) * 1024 + t] = pkrtz(v.z, v.w);
  }
  __syncthreads();

  // packed series pair: lo = f8*8 + 2*wv, hi = +1
  uint p[16];
  {
    const uint* src = sm + (wv << 10);
#pragma unroll
    for (int q = 0; q < 4; ++q) {
      uint4 v = *(const uint4*)(src + (q << 8) + (lane << 2));
      p[q * 4 + 0] = v.x; p[q * 4 + 1] = v.y;
      p[q * 4 + 2] = v.z; p[q * 4 + 3] = v.w;
    }
  }

  const int addr_nx = ((lane + 1) & 63) << 2;
  const int addr63  = (lane ^ 63) << 2;
  const bool is63 = (lane == 63);

  // ============== packed per-series stats (both series at once) ===========
  // tb values at t = 0, 256, 512, 767, 1023 (packed, uniform)
  uint tb0p = irdl(p[0], 0);
  uint tb1p = irdl(p[4], 0);
  uint tb2p = irdl(p[8], 0);
  uint tb3p = irdl(p[11], 63);
  uint tb4p = irdl(p[15], 63);

  // raw moments, packed f16
  h2 s1h = {0, 0}, s2h = {0, 0}, s3h = {0, 0}, s4h = {0, 0};
#pragma unroll
  for (int r = 0; r < 16; ++r) {
    h2 v = u2h(p[r]);
    h2 v2 = v * v;
    s1h += v;
    s2h += v2;
    s3h += v2 * v;
    s4h += v2 * v2;
  }
  uint s1r = red_sum_pk(h2u(s1h));
  const _Float16 inv1024 = (_Float16)(1.0f / 1024.0f);
  h2 invv = {inv1024, inv1024};
  uint meanp = irdl(h2u(u2h(s1r) * invv), 0);

  // counts: 1 v_cmp_gt_f16 per series per reg; hi half via one lshr per reg
  const uint tb0hh = tb0p >> 16, tb1hh = tb1p >> 16, tb2hh = tb2p >> 16;
  const uint tb3hh = tb3p >> 16, tb4hh = tb4p >> 16, meanhh = meanp >> 16;
  int cposA = 0, cposB = 0, cmA = 0, cmB = 0;
  int c0A = 0, c0B = 0, c1A = 0, c1B = 0, c2A = 0, c2B = 0;
  int c3A = 0, c3B = 0, c4A = 0, c4B = 0;
#pragma unroll
  for (int r = 0; r < 16; ++r) {
    _Float16 a = u2h(p[r]).x;
    _Float16 bb = u2h(p[r] >> 16).x;
    cposA += __popcll(__ballot(a > (_Float16)0));
    cposB += __popcll(__ballot(bb > (_Float16)0));
    cmA += __popcll(__ballot(a > u2h(meanp).x));
    cmB += __popcll(__ballot(bb > u2h(meanhh).x));
    c0A += __popcll(__ballot(a > u2h(tb0p).x));
    c0B += __popcll(__ballot(bb > u2h(tb0hh).x));
    c1A += __popcll(__ballot(a > u2h(tb1p).x));
    c1B += __popcll(__ballot(bb > u2h(tb1hh).x));
    c2A += __popcll(__ballot(a > u2h(tb2p).x));
    c2B += __popcll(__ballot(bb > u2h(tb2hh).x));
    c3A += __popcll(__ballot(a > u2h(tb3p).x));
    c3B += __popcll(__ballot(bb > u2h(tb3hh).x));
    c4A += __popcll(__ballot(a > u2h(tb4p).x));
    c4B += __popcll(__ballot(bb > u2h(tb4hh).x));
  }

  // diffs d_t = x[t]-x[t+1], t in [1,1022], packed; sum telescopes.
  uint j1 = irdl(p[4], 0), j2 = irdl(p[8], 0), j3 = irdl(p[12], 0);
  h2 sadh = {0, 0}, sddh = {0, 0};
#pragma unroll
  for (int q = 0; q < 4; ++q) {
    uint nv = bpermu(addr_nx, p[q * 4]);
    if (q == 0) nv = is63 ? j1 : nv;
    if (q == 1) nv = is63 ? j2 : nv;
    if (q == 2) nv = is63 ? j3 : nv;
#pragma unroll
    for (int i = 0; i < 4; ++i) {
      uint xn = (i < 3) ? p[q * 4 + i + 1] : nv;
      uint dvu = h2u(u2h(p[q * 4 + i]) - u2h(xn));
      if (q == 0 && i == 0) dvu = csel(dvu, 0u, KML0);   // t=0 excluded
      if (q == 3 && i == 3) dvu = csel(dvu, 0u, KML63);  // t=1023 excluded
      h2 dv = u2h(dvu);
      sadh += u2h(dvu & 0x7FFF7FFFu);
      sddh += dv * dv;
    }
  }
  uint s2r = red_sum_pk(h2u(s2h));
  uint s3r = red_sum_pk(h2u(s3h));
  uint s4r = red_sum_pk(h2u(s4h));
  uint sadr = red_sum_pk(h2u(sadh));
  uint sddr = red_sum_pk(h2u(sddh));
  uint x1p = irdl(p[1], 0), x1023p = irdl(p[15], 63);
  uint SDp = irdl(h2u(u2h(x1p) - u2h(x1023p)), 0);

  if (lane == 0) {
    uint* rs = rawstash + wv * 20;
    rs[0] = meanp; rs[1] = s2r; rs[2] = s3r; rs[3] = s4r;
    rs[4] = sadr;  rs[5] = sddr; rs[6] = SDp;
    rs[7] = tb0p;  rs[8] = tb1p; rs[9] = tb2p; rs[10] = tb3p; rs[11] = tb4p;
    rs[12] = (uint)(cposA | (cposB << 16));
    rs[13] = (uint)(cmA | (cmB << 16));
    rs[14] = (uint)(c0A | (c0B << 16));
    rs[15] = (uint)(c1A | (c1B << 16));
    rs[16] = (uint)(c2A | (c2B << 16));
    rs[17] = (uint)(c3A | (c3B << 16));
    rs[18] = (uint)(c4A | (c4B << 16));
  }

  // ================= packed sort (both series at once) =====================
  sort16p(p);
  splitp<1>(p, KM1);  merge16p(p);
  splitp<3>(p, KM2);  xstp<1>(p, KM1); merge16p(p);
  splitp<7>(p, KM4);  xstp<2>(p, KM2); xstp<1>(p, KM1); merge16p(p);
  splitp<15>(p, KM8); xstp<4>(p, KM4); xstp<2>(p, KM2); xstp<1>(p, KM1);
  merge16p(p);
  splitp<31>(p, KM16); xstp<8>(p, KM8); xstp<4>(p, KM4); xstp<2>(p, KM2);
  xstp<1>(p, KM1); merge16p(p);
  split63p(p, KM32, addr63);
  xstp<16>(p, KM16);

  // Pruned tail: 16-lane groups hold rank blocks {0-255,256-511,512-767,768-1023}.
  uint mnv = p[0], mxv = p[0];
#pragma unroll
  for (int r = 1; r < 16; ++r) { mnv = pmin(mnv, p[r]); mxv = pmax(mxv, p[r]); }
  mnv = pmin(mnv, exu<1>(mnv)); mxv = pmax(mxv, exu<1>(mxv));
  mnv = pmin(mnv, exu<2>(mnv)); mxv = pmax(mxv, exu<2>(mxv));
  mnv = pmin(mnv, exu<4>(mnv)); mxv = pmax(mxv, exu<4>(mxv));
  mnv = pmin(mnv, exu<8>(mnv)); mxv = pmax(mxv, exu<8>(mxv));

  uint g0n = irdl(mnv, 0);    // rank 0    (min)
  uint g1n = irdl(mnv, 16);   // rank 256  (q1)
  uint g2n = irdl(mnv, 32);   // rank 512  (q2)
  uint g2x = irdl(mxv, 32);   // rank 767  (q3)
  uint g3x = irdl(mxv, 48);   // rank 1023 (max)

  // ---- patch sort-derived outputs into the stash (per wave, lane0) ----
  if (lane == 0) {
#pragma unroll
    for (int s = 0; s < 2; ++s) {
      int sh = s << 4;
      float mnf = (float)u2h(g0n >> sh).x;
      float q1f = (float)u2h(g1n >> sh).x;
      float q2f = (float)u2h(g2n >> sh).x;
      float q3f = (float)u2h(g2x >> sh).x;
      float mxf = (float)u2h(g3x >> sh).x;
      float* o = stash + ((wv << 1) + s) * 30;
      o[1]  = mnf;
      o[2]  = mxf;
      o[11] = q1f;
      o[12] = q2f;
      o[13] = q3f;
      o[20] = fmaxf(fabsf(mnf), fabsf(mxf));
    }
  }
  __syncthreads();

  // ---- block-level epilogue: tid 0..7 -> one series each ----
  if (tid < 8) {
    const uint* rs = rawstash + (tid >> 1) * 20;
    const int sh = (tid & 1) << 4;
    float mean = (float)u2h(rs[0] >> sh).x;
    float s2   = (float)u2h(rs[1] >> sh).x;
    float s3   = (float)u2h(rs[2] >> sh).x;
    float s4   = (float)u2h(rs[3] >> sh).x;
    float sad  = (float)u2h(rs[4] >> sh).x;
    float sdd  = (float)u2h(rs[5] >> sh).x;
    float SD   = (float)u2h(rs[6] >> sh).x;
    float tb0  = (float)u2h(rs[7] >> sh).x;
    float tb1  = (float)u2h(rs[8] >> sh).x;
    float tb2  = (float)u2h(rs[9] >> sh).x;
    float tb3  = (float)u2h(rs[10] >> sh).x;
    float tb4  = (float)u2h(rs[11] >> sh).x;
    float fcpos = (float)((rs[12] >> sh) & 0xFFFF);
    float fcm   = (float)((rs[13] >> sh) & 0xFFFF);
    float fc0   = (float)((rs[14] >> sh) & 0xFFFF);
    float fc1   = (float)((rs[15] >> sh) & 0xFFFF);
    float fc2   = (float)((rs[16] >> sh) & 0xFFFF);
    float fc3   = (float)((rs[17] >> sh) & 0xFFFF);
    float fc4   = (float)((rs[18] >> sh) & 0xFFFF);

    float ex2 = s2 * (1.0f / 1024.0f);
    float rms = __builtin_amdgcn_sqrtf(fmaxf(ex2, 0.f));
    float var = fmaxf(ex2 - mean * mean, 0.f);
    float stdv = __builtin_amdgcn_sqrtf(var);
    float m2 = mean * mean;
    float m3c = s3 - 3.f * mean * s2 + 2048.f * m2 * mean;
    const float coef3 = (float)(1024.0 / (1023.0 * 1022.0));
    float den3 = stdv * stdv * stdv;
    float skew = (den3 > 0.f) ? coef3 * m3c * __builtin_amdgcn_rcpf(den3) : 0.f;
    float k4c = s4 - 4.f * mean * s3 + 6.f * m2 * s2 - 3072.f * m2 * m2;
    float s2c = s2 - 1024.f * m2;
    float k22 = s2c * s2c;
    const float alpha = (float)(1024.0 * 1025.0 * 1023.0 / (1022.0 * 1021.0));
    const float rightc = (float)(3.0 * 1023.0 * 1023.0 / (1022.0 * 1021.0));
    float kurt = (k22 > 0.f) ? alpha * k4c * __builtin_amdgcn_rcpf(k22) - rightc
                             : -rightc;

    float* o = stash + tid * 30;
    o[0] = mean;  o[3] = rms;  o[4] = var;  o[5] = stdv;
    o[6] = skew;  o[7] = kurt;
    o[8] = SD * (1.0f / 1022.0f);
    o[9] = SD;
    o[10] = sad * (1.0f / 1022.0f);
    o[14] = tb0;  o[15] = tb1; o[16] = tb2; o[17] = tb3; o[18] = tb4;
    o[19] = s2;
    o[21] = sad;
    o[22] = __builtin_amdgcn_sqrtf(fmaxf(sdd, 0.f));
    o[23] = fcpos; o[24] = fcm;
    o[25] = fc0;   o[26] = fc1; o[27] = fc2; o[28] = fc3; o[29] = fc4;
  }
  __syncthreads();

  // ---- coalesced block output: 8 rows x 30 floats = 960 B contiguous ----
  if (tid < 240) {
    size_t base = ((size_t)((b << 5) + (f8 << 3))) * 30;
    out[base + tid] = stash[tid];
  }
}

extern "C" void kernel_launch(void* const* d_in, const int* in_sizes, int n_in,
                              void* d_out, int out_size, void* d_ws, size_t ws_size,
                              hipStream_t stream) {
  const float* x = (const float*)d_in[0];
  float* out = (float*)d_out;
  hipLaunchKernelGGL(feat_fused, dim3(2048), dim3(256), 0, stream, x, out);
}